// Round 9
// baseline (856.700 us; speedup 1.0000x reference)
//
#include <hip/hip_runtime.h>
#include <hip/hip_bf16.h>
#include <cstdint>
#include <cstddef>

#define V_ 8192
#define D_ 1024
#define B_ 32
#define T_ 128
#define NBLK 16
#define NWORK 240
#define SENT 0x7FC0u   // bf16 NaN — impossible tanh output

typedef __attribute__((ext_vector_type(8))) short bf16x8;
typedef __attribute__((ext_vector_type(4))) float f32x4;

__device__ __forceinline__ short f2bf(float f) {
  union { float f; unsigned u; } v; v.f = f;
  unsigned r = v.u + 0x7fffu + ((v.u >> 16) & 1u);
  return (short)(r >> 16);
}

__device__ __forceinline__ float bf2f(unsigned short u) {
  union { unsigned u; float f; } c; c.u = ((unsigned)u) << 16;
  return c.f;
}

// tanh(x) = 1 - 2/(exp2(2x*log2e)+1); exact at +/-inf, ~1e-7 abs err
__device__ __forceinline__ float fast_tanh(float x) {
  float t = __builtin_amdgcn_exp2f(x * 2.8853900817779268f);
  return 1.0f - 2.0f * __builtin_amdgcn_rcpf(t + 1.0f);
}

// async global->LDS, 16B per lane. lds base must be wave-uniform.
__device__ __forceinline__ void lds_load16(const void* g, void* l) {
  __builtin_amdgcn_global_load_lds(
      (const __attribute__((address_space(1))) unsigned int*)g,
      (__attribute__((address_space(3))) unsigned int*)l,
      16, 0, 0);
}

// ---------- f32 -> bf16 conversion ----------
__global__ __launch_bounds__(256) void conv_bf16_k(const float* __restrict__ in,
                                                   short* __restrict__ out, int n4) {
  int i = blockIdx.x * 256 + threadIdx.x;  // one float4 per thread
  if (i >= n4) return;
  float4 v = reinterpret_cast<const float4*>(in)[i];
  short4 o;
  o.x = f2bf(v.x); o.y = f2bf(v.y); o.z = f2bf(v.z); o.w = f2bf(v.w);
  reinterpret_cast<short4*>(out)[i] = o;
}

// ---------- W_hh split: Rb = bf16(W_hh, zero diag), Wdiag = diag(W_hh) f32 ----------
__global__ __launch_bounds__(256) void conv_whh(const float* __restrict__ W,
                                                short* __restrict__ Rb,
                                                float* __restrict__ Wdiag) {
  int i = blockIdx.x * 256 + threadIdx.x;   // over D*D = 1048576
  int n = i >> 10;
  int k = i & (D_ - 1);
  float w = W[i];
  Rb[i] = f2bf(k == n ? 0.0f : w);
  if (k == n) Wdiag[n] = w;
}

// ---------- poison Hb slots 1..128 with bf16-NaN sentinel (agent stores: no L2 lines) ----------
__global__ __launch_bounds__(256) void poison_h(unsigned long long* __restrict__ p, int n8) {
  int i = blockIdx.x * 256 + threadIdx.x;   // u64 chunks
  if (i < n8)
    __hip_atomic_store(p + i, 0x7FC07FC07FC07FC0ull,
                       __ATOMIC_RELAXED, __HIP_MEMORY_SCOPE_AGENT);
}

// ---------- h0 -> Hb slot0 (agent); flags=0; transpose idx ----------
__global__ __launch_bounds__(256) void init_h(const float* __restrict__ h0,
                                              const int* __restrict__ idx,
                                              short* __restrict__ Hb0,
                                              unsigned* __restrict__ flags,
                                              int* __restrict__ idxT) {
  int i = blockIdx.x * 256 + threadIdx.x;   // over 16384 (u32 pairs)
  if (i < (B_ * D_) / 2) {
    unsigned lo = (unsigned short)f2bf(h0[2 * i]);
    unsigned hi = (unsigned short)f2bf(h0[2 * i + 1]);
    __hip_atomic_store((unsigned*)Hb0 + i, lo | (hi << 16),
                       __ATOMIC_RELAXED, __HIP_MEMORY_SCOPE_AGENT);
  }
  if (i < 64)
    __hip_atomic_store(flags + i, 0u, __ATOMIC_RELAXED, __HIP_MEMORY_SCOPE_AGENT);
  if (i < T_ * B_) {                        // idxT[t][b] = idx[b][t]
    int b = i & (B_ - 1);
    int t = i >> 5;
    idxT[i] = idx[b * T_ + t];
  }
}

// ---------- Wtb[v][d] = bf16(W_ih[d][v] + b_ih[d] + b_hh[d]) ----------
__global__ __launch_bounds__(256) void wtrans(const float* __restrict__ W,
                                              const float* __restrict__ b_ih,
                                              const float* __restrict__ b_hh,
                                              short* __restrict__ Wtb) {
  __shared__ float tile[32][33];
  const int tx = threadIdx.x & 31;
  const int ty = threadIdx.x >> 5;          // 0..7
  const int v0 = blockIdx.x * 32;
  const int d0 = blockIdx.y * 32;
#pragma unroll
  for (int i = 0; i < 32; i += 8)
    tile[ty + i][tx] = W[(size_t)(d0 + ty + i) * V_ + v0 + tx];
  __syncthreads();
  const int d = d0 + tx;
  const float bias = b_ih[d] + b_hh[d];
#pragma unroll
  for (int i = 0; i < 32; i += 8)
    Wtb[(size_t)(v0 + ty + i) * D_ + d] = f2bf(tile[tx][ty + i] + bias);
}

// ---------- fused: 16 recurrence blocks + 240 gemm-worker blocks ----------
// rnn role (blocks 0..15): round-8 sentinel dataflow, unchanged, plus an
// unconditional flags[blk]=t+1 publish after the store-drain barrier.
// worker role (blocks 16..255): loop over 2048 logits tiles (tm-ascending);
// wait for flags[0..15] >= 4*tm+4, then compute the 128x128 tile with the
// proven swizzled-LDS gemm and write C+bias. Workers' Hb reads are plain
// (first touch after readiness; dispatch-begin invalidate cleared old lines).
__global__ __launch_bounds__(512) void rnn_fused(const short* __restrict__ Rb,
                                                 const float* __restrict__ Wdiag,
                                                 const float* __restrict__ h0,
                                                 const short* __restrict__ Wtb,
                                                 const int* __restrict__ idxT,
                                                 short* __restrict__ Hb,
                                                 unsigned* __restrict__ flags,
                                                 const short* __restrict__ Wb,
                                                 const float* __restrict__ b_o,
                                                 float* __restrict__ C) {
  __shared__ __align__(16) char smem[65536];
  const int tid = threadIdx.x;

  if (blockIdx.x < NBLK) {
    // ================= RNN role =================
    f32x4 (*part)[2][4][64] = reinterpret_cast<f32x4 (*)[2][4][64]>(smem);
    const int lane = tid & 63;
    const int w = tid >> 6;                  // 0..7, wave-uniform
    const int n0 = blockIdx.x * 64;
    const int fcol = lane & 15;
    const int l16 = lane >> 4;               // 0..3
    const int ks = w * 128;

    // persistent B fragments: Rb rows n0..n0+63, this wave's K-slice
    bf16x8 bfrag[4][4];
#pragma unroll
    for (int ni = 0; ni < 4; ++ni) {
      const short* bp = Rb + (size_t)(n0 + ni * 16 + fcol) * D_ + ks + l16 * 8;
#pragma unroll
      for (int kk = 0; kk < 4; ++kk)
        bfrag[ni][kk] = *reinterpret_cast<const bf16x8*>(bp + kk * 32);
    }

    const int mi_e = w >> 2;                 // 0..1
    const int ni_e = w & 3;                  // 0..3
    const int n_e = n0 + ni_e * 16 + fcol;
    const int mbase = mi_e * 16 + l16 * 4;   // +q -> batch row
    const float wd = Wdiag[n_e];
    float hf[4];
#pragma unroll
    for (int q = 0; q < 4; ++q)
      hf[q] = h0[(size_t)(mbase + q) * D_ + n_e];

    float xv[4];
    {
      int4 tk = *reinterpret_cast<const int4*>(idxT + mbase);
      xv[0] = bf2f(*(const unsigned short*)(Wtb + (size_t)tk.x * D_ + n_e));
      xv[1] = bf2f(*(const unsigned short*)(Wtb + (size_t)tk.y * D_ + n_e));
      xv[2] = bf2f(*(const unsigned short*)(Wtb + (size_t)tk.z * D_ + n_e));
      xv[3] = bf2f(*(const unsigned short*)(Wtb + (size_t)tk.w * D_ + n_e));
    }

    union U16 { unsigned long long q[2]; bf16x8 v; };

    for (int t = 0; t < T_; ++t) {
      // (A) poll this wave's A-fragment of Hb slot t until sentinel-free
      const short* hp = Hb + (size_t)t * (B_ * D_);
      unsigned long long q[16];
      while (true) {
#pragma unroll
        for (int mi = 0; mi < 2; ++mi) {
          const short* ap = hp + (size_t)(mi * 16 + fcol) * D_ + ks + l16 * 8;
#pragma unroll
          for (int kk = 0; kk < 4; ++kk) {
            q[mi * 8 + kk * 2 + 0] =
                __hip_atomic_load((const unsigned long long*)(ap + kk * 32),
                                  __ATOMIC_RELAXED, __HIP_MEMORY_SCOPE_AGENT);
            q[mi * 8 + kk * 2 + 1] =
                __hip_atomic_load((const unsigned long long*)(ap + kk * 32 + 4),
                                  __ATOMIC_RELAXED, __HIP_MEMORY_SCOPE_AGENT);
          }
        }
        unsigned bad = 0u;
#pragma unroll
        for (int i = 0; i < 16; ++i) {
          unsigned lo = (unsigned)(q[i] & 0xFFFFFFFFull);
          unsigned hi = (unsigned)(q[i] >> 32);
          bad |= ((lo & 0xFFFFu) == SENT);
          bad |= ((lo >> 16) == SENT);
          bad |= ((hi & 0xFFFFu) == SENT);
          bad |= ((hi >> 16) == SENT);
        }
        if (!__any((int)bad)) break;
      }
      bf16x8 af[2][4];
#pragma unroll
      for (int mi = 0; mi < 2; ++mi)
#pragma unroll
        for (int kk = 0; kk < 4; ++kk) {
          U16 u;
          u.q[0] = q[mi * 8 + kk * 2 + 0];
          u.q[1] = q[mi * 8 + kk * 2 + 1];
          af[mi][kk] = u.v;
        }

      // (B) MFMA partials
#pragma unroll
      for (int mi = 0; mi < 2; ++mi)
#pragma unroll
        for (int ni = 0; ni < 4; ++ni) {
          f32x4 a = {0.f, 0.f, 0.f, 0.f};
#pragma unroll
          for (int kk = 0; kk < 4; ++kk)
            a = __builtin_amdgcn_mfma_f32_16x16x32_bf16(af[mi][kk], bfrag[ni][kk], a, 0, 0, 0);
          part[w][mi][ni][lane] = a;
        }
      __syncthreads();                       // sync1: partials complete

      // (C) reduce across K-slices; tanh; publish h slot t+1
      f32x4 s = part[0][mi_e][ni_e][lane];
#pragma unroll
      for (int r = 1; r < 8; ++r) s += part[r][mi_e][ni_e][lane];

      short* hn = Hb + (size_t)(t + 1) * (B_ * D_);
#pragma unroll
      for (int q2 = 0; q2 < 4; ++q2) {
        float v = fast_tanh(xv[q2] + s[q2] + hf[q2] * wd);
        hf[q2] = v;
        __hip_atomic_store((unsigned short*)(hn + (size_t)(mbase + q2) * D_ + n_e),
                           (unsigned short)f2bf(v),
                           __ATOMIC_RELAXED, __HIP_MEMORY_SCOPE_AGENT);
      }

      // (D) prefetch next step's X gather
      if (t < T_ - 1) {
        int4 tk = *reinterpret_cast<const int4*>(idxT + (t + 1) * B_ + mbase);
        xv[0] = bf2f(*(const unsigned short*)(Wtb + (size_t)tk.x * D_ + n_e));
        xv[1] = bf2f(*(const unsigned short*)(Wtb + (size_t)tk.y * D_ + n_e));
        xv[2] = bf2f(*(const unsigned short*)(Wtb + (size_t)tk.z * D_ + n_e));
        xv[3] = bf2f(*(const unsigned short*)(Wtb + (size_t)tk.w * D_ + n_e));
      }

      __syncthreads();                       // sync2: all waves' h-stores drained
      if (tid == 0)                          // unconditional: reaches 128 for workers
        __hip_atomic_store(flags + blockIdx.x, (unsigned)(t + 1),
                           __ATOMIC_RELAXED, __HIP_MEMORY_SCOPE_AGENT);
    }
    return;
  }

  // ================= GEMM worker role =================
  short* As = reinterpret_cast<short*>(smem);            // 16 KB
  short* Bs = reinterpret_cast<short*>(smem + 16384);    // 16 KB
  const short* A = Hb + B_ * D_;                          // slot 1 onward
  const int wid = blockIdx.x - NBLK;                      // 0..239
  const int lane = tid & 63;
  const int w4 = (tid >> 6) & 3;                          // wave id within 0..3
  const int wr = w4 >> 1, wc = w4 & 1;

  for (int idx = wid; idx < 2048; idx += NWORK) {
    const int tm = idx >> 6, tn = idx & 63;
    // wave 0 waits until all 16 rnn blocks have published slot 4*tm+4
    if (tid < 64) {
      const unsigned need = (unsigned)(4 * tm + 4);
      while (true) {
        unsigned f = need;
        if (tid < NBLK)
          f = __hip_atomic_load(flags + tid, __ATOMIC_RELAXED,
                                __HIP_MEMORY_SCOPE_AGENT);
        if (__all((int)(f >= need))) break;
        __builtin_amdgcn_s_sleep(8);
      }
    }
    __syncthreads();

    const int r0 = tm * 128;
    const int c0 = tn * 128;
    f32x4 acc[4][4] = {};

    for (int k0 = 0; k0 < D_; k0 += 64) {
      if (tid < 256) {
#pragma unroll
        for (int i = 0; i < 4; ++i) {
          int c = tid + 256 * i;
          int cb = (tid & ~63) + 256 * i;
          int row = c >> 3;
          int colc = ((c & 7) ^ (row & 7)) * 8;
          lds_load16(A + (size_t)(r0 + row) * D_ + k0 + colc, &As[cb * 8]);
          lds_load16(Wb + (size_t)(c0 + row) * D_ + k0 + colc, &Bs[cb * 8]);
        }
        asm volatile("s_waitcnt vmcnt(0)" ::: "memory");
      }
      __syncthreads();

      if (tid < 256) {
#pragma unroll
        for (int kk = 0; kk < 2; ++kk) {
          bf16x8 af[4], bfr[4];
          const int fcol = lane & 15;
          const int chunk = (kk * 4 + (lane >> 4)) ^ (fcol & 7);
#pragma unroll
          for (int i = 0; i < 4; ++i)
            af[i] = *reinterpret_cast<const bf16x8*>(&As[(wr * 64 + i * 16 + fcol) * 64 + chunk * 8]);
#pragma unroll
          for (int j = 0; j < 4; ++j)
            bfr[j] = *reinterpret_cast<const bf16x8*>(&Bs[(wc * 64 + j * 16 + fcol) * 64 + chunk * 8]);
#pragma unroll
          for (int i = 0; i < 4; ++i)
#pragma unroll
            for (int j = 0; j < 4; ++j)
              acc[i][j] = __builtin_amdgcn_mfma_f32_16x16x32_bf16(af[i], bfr[j], acc[i][j], 0, 0, 0);
        }
      }
      __syncthreads();
    }

    if (tid < 256) {
      const int fcol = lane & 15;
      const int frow = (lane >> 4) * 4;
#pragma unroll
      for (int i = 0; i < 4; ++i) {
        int row = r0 + wr * 64 + i * 16 + frow;
#pragma unroll
        for (int j = 0; j < 4; ++j) {
          int col = c0 + wc * 64 + j * 16 + fcol;
          float bias = b_o[col];
#pragma unroll
          for (int q = 0; q < 4; ++q)
            C[(size_t)(row + q) * V_ + col] = acc[i][j][q] + bias;
        }
      }
    }
    // next iteration's poll-barrier orders As/Bs reuse
  }
}

// ---------- in-place log-softmax over rows of 8192 ----------
__global__ __launch_bounds__(256) void logsoftmax(float* __restrict__ out) {
  __shared__ float red[4];
  __shared__ float red2[4];
  float* row = out + (size_t)blockIdx.x * V_;
  const int tid = threadIdx.x;

  float4 v[8];
  float mx = -1e30f;
#pragma unroll
  for (int i = 0; i < 8; ++i) {
    v[i] = *reinterpret_cast<const float4*>(&row[(i * 256 + tid) * 4]);
    mx = fmaxf(mx, fmaxf(fmaxf(v[i].x, v[i].y), fmaxf(v[i].z, v[i].w)));
  }
#pragma unroll
  for (int off = 32; off > 0; off >>= 1) mx = fmaxf(mx, __shfl_xor(mx, off, 64));
  if ((tid & 63) == 0) red[tid >> 6] = mx;
  __syncthreads();
  mx = fmaxf(fmaxf(red[0], red[1]), fmaxf(red[2], red[3]));

  float sum = 0.f;
#pragma unroll
  for (int i = 0; i < 8; ++i)
    sum += expf(v[i].x - mx) + expf(v[i].y - mx) + expf(v[i].z - mx) + expf(v[i].w - mx);
#pragma unroll
  for (int off = 32; off > 0; off >>= 1) sum += __shfl_xor(sum, off, 64);
  if ((tid & 63) == 0) red2[tid >> 6] = sum;
  __syncthreads();
  sum = (red2[0] + red2[1]) + (red2[2] + red2[3]);

  const float lse = mx + logf(sum);
#pragma unroll
  for (int i = 0; i < 8; ++i) {
    float4 o = v[i];
    o.x -= lse; o.y -= lse; o.z -= lse; o.w -= lse;
    *reinterpret_cast<float4*>(&row[(i * 256 + tid) * 4]) = o;
  }
}

extern "C" void kernel_launch(void* const* d_in, const int* in_sizes, int n_in,
                              void* d_out, int out_size, void* d_ws, size_t ws_size,
                              hipStream_t stream) {
  const int* idx = (const int*)d_in[0];
  const float* h0 = (const float*)d_in[1];
  const float* W_ih = (const float*)d_in[2];
  const float* b_ih = (const float*)d_in[3];
  const float* W_hh = (const float*)d_in[4];
  const float* b_hh = (const float*)d_in[5];
  const float* W_ho = (const float*)d_in[6];
  const float* b_o = (const float*)d_in[7];
  float* out = (float*)d_out;

  // workspace layout (~44.2 MB):
  // Hb  bf16 [129][32][1024]   8454144 B @ 0
  // Wb  bf16 [8192][1024]     16777216 B @ 8454144
  // Rb  bf16 [1024][1024]      2097152 B @ 25231360
  // Wdiag f32 [1024]              4096 B @ 27328512
  // Wtb bf16 [8192][1024]     16777216 B @ 27332608
  // flags u32 [64]                4096 B @ 44109824
  // idxT int [128][32]           16384 B @ 44113920
  char* ws = (char*)d_ws;
  short* Hb = (short*)ws;
  short* Wb = (short*)(ws + 8454144);
  short* Rb = (short*)(ws + 25231360);
  float* Wdiag = (float*)(ws + 27328512);
  short* Wtb = (short*)(ws + 27332608);
  unsigned* flags = (unsigned*)(ws + 44109824);
  int* idxT = (int*)(ws + 44113920);

  conv_bf16_k<<<dim3(8192), dim3(256), 0, stream>>>(W_ho, Wb, (V_ * D_) / 4);
  conv_whh<<<dim3(4096), dim3(256), 0, stream>>>(W_hh, Rb, Wdiag);
  // poison slots 1..128: 8.39 MB = 1048576 u64
  poison_h<<<dim3(4096), dim3(256), 0, stream>>>(
      (unsigned long long*)(Hb + B_ * D_), (T_ * B_ * D_) / 4);
  init_h<<<dim3(64), dim3(256), 0, stream>>>(h0, idx, Hb, flags, idxT);
  wtrans<<<dim3(V_ / 32, D_ / 32), dim3(256), 0, stream>>>(W_ih, b_ih, b_hh, Wtb);

  rnn_fused<<<dim3(NBLK + NWORK), dim3(512), 0, stream>>>(
      Rb, Wdiag, h0, Wtb, idxT, Hb, flags, Wb, b_o, out);

  logsoftmax<<<dim3(T_ * B_), dim3(256), 0, stream>>>(out);
}

// Round 10
// 840.769 us; speedup vs baseline: 1.0189x; 1.0189x over previous
//
#include <hip/hip_runtime.h>
#include <hip/hip_bf16.h>
#include <cstdint>
#include <cstddef>

#define V_ 8192
#define D_ 1024
#define B_ 32
#define T_ 128
#define NBLK 16
#define NWORK 240
#define SENT 0x7FC0u   // bf16 NaN — impossible tanh output

typedef __attribute__((ext_vector_type(8))) short bf16x8;
typedef __attribute__((ext_vector_type(4))) float f32x4;

__device__ __forceinline__ short f2bf(float f) {
  union { float f; unsigned u; } v; v.f = f;
  unsigned r = v.u + 0x7fffu + ((v.u >> 16) & 1u);
  return (short)(r >> 16);
}

__device__ __forceinline__ float bf2f(unsigned short u) {
  union { unsigned u; float f; } c; c.u = ((unsigned)u) << 16;
  return c.f;
}

// tanh(x) = 1 - 2/(exp2(2x*log2e)+1); exact at +/-inf, ~1e-7 abs err
__device__ __forceinline__ float fast_tanh(float x) {
  float t = __builtin_amdgcn_exp2f(x * 2.8853900817779268f);
  return 1.0f - 2.0f * __builtin_amdgcn_rcpf(t + 1.0f);
}

// dense VALU burn: 4 chains x 64 dependent FMAs (~256cy). Keeps the CU's
// VALU pipe busy so the power governor holds clocks up (DVFS pinning).
__device__ __forceinline__ void busy_fma(float z[4]) {
#pragma unroll
  for (int i = 0; i < 64; ++i) {
    z[0] = __builtin_fmaf(z[0], 1.0000001f, 1e-7f);
    z[1] = __builtin_fmaf(z[1], 1.0000002f, 1e-7f);
    z[2] = __builtin_fmaf(z[2], 1.0000003f, 1e-7f);
    z[3] = __builtin_fmaf(z[3], 1.0000004f, 1e-7f);
  }
  asm volatile("" :: "v"(z[0]), "v"(z[1]), "v"(z[2]), "v"(z[3]));
}

// async global->LDS, 16B per lane. lds base must be wave-uniform.
__device__ __forceinline__ void lds_load16(const void* g, void* l) {
  __builtin_amdgcn_global_load_lds(
      (const __attribute__((address_space(1))) unsigned int*)g,
      (__attribute__((address_space(3))) unsigned int*)l,
      16, 0, 0);
}

// ---------- f32 -> bf16 conversion ----------
__global__ __launch_bounds__(256) void conv_bf16_k(const float* __restrict__ in,
                                                   short* __restrict__ out, int n4) {
  int i = blockIdx.x * 256 + threadIdx.x;  // one float4 per thread
  if (i >= n4) return;
  float4 v = reinterpret_cast<const float4*>(in)[i];
  short4 o;
  o.x = f2bf(v.x); o.y = f2bf(v.y); o.z = f2bf(v.z); o.w = f2bf(v.w);
  reinterpret_cast<short4*>(out)[i] = o;
}

// ---------- W_hh split: Rb = bf16(W_hh, zero diag), Wdiag = diag(W_hh) f32 ----------
__global__ __launch_bounds__(256) void conv_whh(const float* __restrict__ W,
                                                short* __restrict__ Rb,
                                                float* __restrict__ Wdiag) {
  int i = blockIdx.x * 256 + threadIdx.x;   // over D*D = 1048576
  int n = i >> 10;
  int k = i & (D_ - 1);
  float w = W[i];
  Rb[i] = f2bf(k == n ? 0.0f : w);
  if (k == n) Wdiag[n] = w;
}

// ---------- poison Hb slots 1..128 with bf16-NaN sentinel (agent stores: no L2 lines) ----------
__global__ __launch_bounds__(256) void poison_h(unsigned long long* __restrict__ p, int n8) {
  int i = blockIdx.x * 256 + threadIdx.x;   // u64 chunks
  if (i < n8)
    __hip_atomic_store(p + i, 0x7FC07FC07FC07FC0ull,
                       __ATOMIC_RELAXED, __HIP_MEMORY_SCOPE_AGENT);
}

// ---------- h0 -> Hb slot0 (agent); flags=0; transpose idx ----------
__global__ __launch_bounds__(256) void init_h(const float* __restrict__ h0,
                                              const int* __restrict__ idx,
                                              short* __restrict__ Hb0,
                                              unsigned* __restrict__ flags,
                                              int* __restrict__ idxT) {
  int i = blockIdx.x * 256 + threadIdx.x;   // over 16384 (u32 pairs)
  if (i < (B_ * D_) / 2) {
    unsigned lo = (unsigned short)f2bf(h0[2 * i]);
    unsigned hi = (unsigned short)f2bf(h0[2 * i + 1]);
    __hip_atomic_store((unsigned*)Hb0 + i, lo | (hi << 16),
                       __ATOMIC_RELAXED, __HIP_MEMORY_SCOPE_AGENT);
  }
  if (i < 64)
    __hip_atomic_store(flags + i, 0u, __ATOMIC_RELAXED, __HIP_MEMORY_SCOPE_AGENT);
  if (i < T_ * B_) {                        // idxT[t][b] = idx[b][t]
    int b = i & (B_ - 1);
    int t = i >> 5;
    idxT[i] = idx[b * T_ + t];
  }
}

// ---------- Wtb[v][d] = bf16(W_ih[d][v] + b_ih[d] + b_hh[d]) ----------
__global__ __launch_bounds__(256) void wtrans(const float* __restrict__ W,
                                              const float* __restrict__ b_ih,
                                              const float* __restrict__ b_hh,
                                              short* __restrict__ Wtb) {
  __shared__ float tile[32][33];
  const int tx = threadIdx.x & 31;
  const int ty = threadIdx.x >> 5;          // 0..7
  const int v0 = blockIdx.x * 32;
  const int d0 = blockIdx.y * 32;
#pragma unroll
  for (int i = 0; i < 32; i += 8)
    tile[ty + i][tx] = W[(size_t)(d0 + ty + i) * V_ + v0 + tx];
  __syncthreads();
  const int d = d0 + tx;
  const float bias = b_ih[d] + b_hh[d];
#pragma unroll
  for (int i = 0; i < 32; i += 8)
    Wtb[(size_t)(v0 + ty + i) * D_ + d] = f2bf(tile[tx][ty + i] + bias);
}

// ---------- fused: 16 recurrence blocks + 240 clock-pinning gemm workers ----------
// rnn role (blocks 0..15): round-8 sentinel dataflow (unchanged; proven).
// worker role (blocks 16..255): busy-FMA spin (pins clocks) until the tile's
// flag gate opens, then the proven swizzled-LDS gemm tile. Wave 0 polls the
// global flags between FMA sweeps; waves 1..7 spin on an LDS `go` word.
__global__ __launch_bounds__(512) void rnn_fused(const short* __restrict__ Rb,
                                                 const float* __restrict__ Wdiag,
                                                 const float* __restrict__ h0,
                                                 const short* __restrict__ Wtb,
                                                 const int* __restrict__ idxT,
                                                 short* __restrict__ Hb,
                                                 unsigned* __restrict__ flags,
                                                 const short* __restrict__ Wb,
                                                 const float* __restrict__ b_o,
                                                 float* __restrict__ C) {
  __shared__ __align__(16) char smem[65536];
  __shared__ unsigned go_s;
  const int tid = threadIdx.x;

  if (blockIdx.x < NBLK) {
    // ================= RNN role =================
    f32x4 (*part)[2][4][64] = reinterpret_cast<f32x4 (*)[2][4][64]>(smem);
    const int lane = tid & 63;
    const int w = tid >> 6;                  // 0..7, wave-uniform
    const int n0 = blockIdx.x * 64;
    const int fcol = lane & 15;
    const int l16 = lane >> 4;               // 0..3
    const int ks = w * 128;

    // persistent B fragments: Rb rows n0..n0+63, this wave's K-slice
    bf16x8 bfrag[4][4];
#pragma unroll
    for (int ni = 0; ni < 4; ++ni) {
      const short* bp = Rb + (size_t)(n0 + ni * 16 + fcol) * D_ + ks + l16 * 8;
#pragma unroll
      for (int kk = 0; kk < 4; ++kk)
        bfrag[ni][kk] = *reinterpret_cast<const bf16x8*>(bp + kk * 32);
    }

    const int mi_e = w >> 2;                 // 0..1
    const int ni_e = w & 3;                  // 0..3
    const int n_e = n0 + ni_e * 16 + fcol;
    const int mbase = mi_e * 16 + l16 * 4;   // +q -> batch row
    const float wd = Wdiag[n_e];
    float hf[4];
#pragma unroll
    for (int q = 0; q < 4; ++q)
      hf[q] = h0[(size_t)(mbase + q) * D_ + n_e];

    float xv[4];
    {
      int4 tk = *reinterpret_cast<const int4*>(idxT + mbase);
      xv[0] = bf2f(*(const unsigned short*)(Wtb + (size_t)tk.x * D_ + n_e));
      xv[1] = bf2f(*(const unsigned short*)(Wtb + (size_t)tk.y * D_ + n_e));
      xv[2] = bf2f(*(const unsigned short*)(Wtb + (size_t)tk.z * D_ + n_e));
      xv[3] = bf2f(*(const unsigned short*)(Wtb + (size_t)tk.w * D_ + n_e));
    }

    union U16 { unsigned long long q[2]; bf16x8 v; };

    for (int t = 0; t < T_; ++t) {
      // (A) poll this wave's A-fragment of Hb slot t until sentinel-free
      const short* hp = Hb + (size_t)t * (B_ * D_);
      unsigned long long q[16];
      while (true) {
#pragma unroll
        for (int mi = 0; mi < 2; ++mi) {
          const short* ap = hp + (size_t)(mi * 16 + fcol) * D_ + ks + l16 * 8;
#pragma unroll
          for (int kk = 0; kk < 4; ++kk) {
            q[mi * 8 + kk * 2 + 0] =
                __hip_atomic_load((const unsigned long long*)(ap + kk * 32),
                                  __ATOMIC_RELAXED, __HIP_MEMORY_SCOPE_AGENT);
            q[mi * 8 + kk * 2 + 1] =
                __hip_atomic_load((const unsigned long long*)(ap + kk * 32 + 4),
                                  __ATOMIC_RELAXED, __HIP_MEMORY_SCOPE_AGENT);
          }
        }
        unsigned bad = 0u;
#pragma unroll
        for (int i = 0; i < 16; ++i) {
          unsigned lo = (unsigned)(q[i] & 0xFFFFFFFFull);
          unsigned hi = (unsigned)(q[i] >> 32);
          bad |= ((lo & 0xFFFFu) == SENT);
          bad |= ((lo >> 16) == SENT);
          bad |= ((hi & 0xFFFFu) == SENT);
          bad |= ((hi >> 16) == SENT);
        }
        if (!__any((int)bad)) break;
      }
      bf16x8 af[2][4];
#pragma unroll
      for (int mi = 0; mi < 2; ++mi)
#pragma unroll
        for (int kk = 0; kk < 4; ++kk) {
          U16 u;
          u.q[0] = q[mi * 8 + kk * 2 + 0];
          u.q[1] = q[mi * 8 + kk * 2 + 1];
          af[mi][kk] = u.v;
        }

      // (B) MFMA partials
#pragma unroll
      for (int mi = 0; mi < 2; ++mi)
#pragma unroll
        for (int ni = 0; ni < 4; ++ni) {
          f32x4 a = {0.f, 0.f, 0.f, 0.f};
#pragma unroll
          for (int kk = 0; kk < 4; ++kk)
            a = __builtin_amdgcn_mfma_f32_16x16x32_bf16(af[mi][kk], bfrag[ni][kk], a, 0, 0, 0);
          part[w][mi][ni][lane] = a;
        }
      __syncthreads();                       // sync1: partials complete

      // (C) reduce across K-slices; tanh; publish h slot t+1
      f32x4 s = part[0][mi_e][ni_e][lane];
#pragma unroll
      for (int r = 1; r < 8; ++r) s += part[r][mi_e][ni_e][lane];

      short* hn = Hb + (size_t)(t + 1) * (B_ * D_);
#pragma unroll
      for (int q2 = 0; q2 < 4; ++q2) {
        float v = fast_tanh(xv[q2] + s[q2] + hf[q2] * wd);
        hf[q2] = v;
        __hip_atomic_store((unsigned short*)(hn + (size_t)(mbase + q2) * D_ + n_e),
                           (unsigned short)f2bf(v),
                           __ATOMIC_RELAXED, __HIP_MEMORY_SCOPE_AGENT);
      }

      // (D) prefetch next step's X gather
      if (t < T_ - 1) {
        int4 tk = *reinterpret_cast<const int4*>(idxT + (t + 1) * B_ + mbase);
        xv[0] = bf2f(*(const unsigned short*)(Wtb + (size_t)tk.x * D_ + n_e));
        xv[1] = bf2f(*(const unsigned short*)(Wtb + (size_t)tk.y * D_ + n_e));
        xv[2] = bf2f(*(const unsigned short*)(Wtb + (size_t)tk.z * D_ + n_e));
        xv[3] = bf2f(*(const unsigned short*)(Wtb + (size_t)tk.w * D_ + n_e));
      }

      __syncthreads();                       // sync2: all waves' h-stores drained
      if (tid == 0)                          // unconditional: reaches 128 for workers
        __hip_atomic_store(flags + blockIdx.x, (unsigned)(t + 1),
                           __ATOMIC_RELAXED, __HIP_MEMORY_SCOPE_AGENT);
    }
    return;
  }

  // ================= GEMM worker role (clock-pinning) =================
  short* As = reinterpret_cast<short*>(smem);            // 16 KB
  short* Bs = reinterpret_cast<short*>(smem + 16384);    // 16 KB
  const short* A = Hb + B_ * D_;                          // slot 1 onward
  const int wid = blockIdx.x - NBLK;                      // 0..239
  const int lane = tid & 63;
  const int w4 = (tid >> 6) & 3;                          // wave id within 0..3
  const int wr = w4 >> 1, wc = w4 & 1;

  if (tid == 0) go_s = 0u;
  __syncthreads();

  float z[4] = {1.0f, 1.1f, 1.2f, 1.3f};
  unsigned seq = 0u;

  for (int idx = wid; idx < 2048; idx += NWORK) {
    const int tm = idx >> 6, tn = idx & 63;
    ++seq;
    // gate: flags[0..15] >= 4*tm+4, with dense-FMA spin to pin clocks
    if (tid < 64) {
      const unsigned need = (unsigned)(4 * tm + 4);
      while (true) {
        unsigned f = need;
        if (tid < NBLK)
          f = __hip_atomic_load(flags + tid, __ATOMIC_RELAXED,
                                __HIP_MEMORY_SCOPE_AGENT);
        if (__all((int)(f >= need))) break;
        busy_fma(z); busy_fma(z); busy_fma(z); busy_fma(z);  // ~0.4 us between polls
      }
      if (tid == 0)
        __hip_atomic_store(&go_s, seq, __ATOMIC_RELAXED,
                           __HIP_MEMORY_SCOPE_WORKGROUP);
    } else {
      while (__hip_atomic_load(&go_s, __ATOMIC_RELAXED,
                               __HIP_MEMORY_SCOPE_WORKGROUP) != seq)
        busy_fma(z);
    }
    __syncthreads();

    const int r0 = tm * 128;
    const int c0 = tn * 128;
    f32x4 acc[4][4] = {};

    for (int k0 = 0; k0 < D_; k0 += 64) {
      if (tid < 256) {
#pragma unroll
        for (int i = 0; i < 4; ++i) {
          int c = tid + 256 * i;
          int cb = (tid & ~63) + 256 * i;
          int row = c >> 3;
          int colc = ((c & 7) ^ (row & 7)) * 8;
          lds_load16(A + (size_t)(r0 + row) * D_ + k0 + colc, &As[cb * 8]);
          lds_load16(Wb + (size_t)(c0 + row) * D_ + k0 + colc, &Bs[cb * 8]);
        }
        asm volatile("s_waitcnt vmcnt(0)" ::: "memory");
      }
      __syncthreads();

      if (tid < 256) {
#pragma unroll
        for (int kk = 0; kk < 2; ++kk) {
          bf16x8 af[4], bfr[4];
          const int fcol = lane & 15;
          const int chunk = (kk * 4 + (lane >> 4)) ^ (fcol & 7);
#pragma unroll
          for (int i = 0; i < 4; ++i)
            af[i] = *reinterpret_cast<const bf16x8*>(&As[(wr * 64 + i * 16 + fcol) * 64 + chunk * 8]);
#pragma unroll
          for (int j = 0; j < 4; ++j)
            bfr[j] = *reinterpret_cast<const bf16x8*>(&Bs[(wc * 64 + j * 16 + fcol) * 64 + chunk * 8]);
#pragma unroll
          for (int i = 0; i < 4; ++i)
#pragma unroll
            for (int j = 0; j < 4; ++j)
              acc[i][j] = __builtin_amdgcn_mfma_f32_16x16x32_bf16(af[i], bfr[j], acc[i][j], 0, 0, 0);
        }
      }
      __syncthreads();
    }

    if (tid < 256) {
      const int fcol = lane & 15;
      const int frow = (lane >> 4) * 4;
#pragma unroll
      for (int i = 0; i < 4; ++i) {
        int row = r0 + wr * 64 + i * 16 + frow;
#pragma unroll
        for (int j = 0; j < 4; ++j) {
          int col = c0 + wc * 64 + j * 16 + fcol;
          float bias = b_o[col];
#pragma unroll
          for (int q = 0; q < 4; ++q)
            C[(size_t)(row + q) * V_ + col] = acc[i][j][q] + bias;
        }
      }
    }
  }
}

// ---------- in-place log-softmax over rows of 8192 ----------
__global__ __launch_bounds__(256) void logsoftmax(float* __restrict__ out) {
  __shared__ float red[4];
  __shared__ float red2[4];
  float* row = out + (size_t)blockIdx.x * V_;
  const int tid = threadIdx.x;

  float4 v[8];
  float mx = -1e30f;
#pragma unroll
  for (int i = 0; i < 8; ++i) {
    v[i] = *reinterpret_cast<const float4*>(&row[(i * 256 + tid) * 4]);
    mx = fmaxf(mx, fmaxf(fmaxf(v[i].x, v[i].y), fmaxf(v[i].z, v[i].w)));
  }
#pragma unroll
  for (int off = 32; off > 0; off >>= 1) mx = fmaxf(mx, __shfl_xor(mx, off, 64));
  if ((tid & 63) == 0) red[tid >> 6] = mx;
  __syncthreads();
  mx = fmaxf(fmaxf(red[0], red[1]), fmaxf(red[2], red[3]));

  float sum = 0.f;
#pragma unroll
  for (int i = 0; i < 8; ++i)
    sum += expf(v[i].x - mx) + expf(v[i].y - mx) + expf(v[i].z - mx) + expf(v[i].w - mx);
#pragma unroll
  for (int off = 32; off > 0; off >>= 1) sum += __shfl_xor(sum, off, 64);
  if ((tid & 63) == 0) red2[tid >> 6] = sum;
  __syncthreads();
  sum = (red2[0] + red2[1]) + (red2[2] + red2[3]);

  const float lse = mx + logf(sum);
#pragma unroll
  for (int i = 0; i < 8; ++i) {
    float4 o = v[i];
    o.x -= lse; o.y -= lse; o.z -= lse; o.w -= lse;
    *reinterpret_cast<float4*>(&row[(i * 256 + tid) * 4]) = o;
  }
}

extern "C" void kernel_launch(void* const* d_in, const int* in_sizes, int n_in,
                              void* d_out, int out_size, void* d_ws, size_t ws_size,
                              hipStream_t stream) {
  const int* idx = (const int*)d_in[0];
  const float* h0 = (const float*)d_in[1];
  const float* W_ih = (const float*)d_in[2];
  const float* b_ih = (const float*)d_in[3];
  const float* W_hh = (const float*)d_in[4];
  const float* b_hh = (const float*)d_in[5];
  const float* W_ho = (const float*)d_in[6];
  const float* b_o = (const float*)d_in[7];
  float* out = (float*)d_out;

  // workspace layout (~44.2 MB):
  // Hb  bf16 [129][32][1024]   8454144 B @ 0
  // Wb  bf16 [8192][1024]     16777216 B @ 8454144
  // Rb  bf16 [1024][1024]      2097152 B @ 25231360
  // Wdiag f32 [1024]              4096 B @ 27328512
  // Wtb bf16 [8192][1024]     16777216 B @ 27332608
  // flags u32 [64]                4096 B @ 44109824
  // idxT int [128][32]           16384 B @ 44113920
  char* ws = (char*)d_ws;
  short* Hb = (short*)ws;
  short* Wb = (short*)(ws + 8454144);
  short* Rb = (short*)(ws + 25231360);
  float* Wdiag = (float*)(ws + 27328512);
  short* Wtb = (short*)(ws + 27332608);
  unsigned* flags = (unsigned*)(ws + 44109824);
  int* idxT = (int*)(ws + 44113920);

  conv_bf16_k<<<dim3(8192), dim3(256), 0, stream>>>(W_ho, Wb, (V_ * D_) / 4);
  conv_whh<<<dim3(4096), dim3(256), 0, stream>>>(W_hh, Rb, Wdiag);
  // poison slots 1..128: 8.39 MB = 1048576 u64
  poison_h<<<dim3(4096), dim3(256), 0, stream>>>(
      (unsigned long long*)(Hb + B_ * D_), (T_ * B_ * D_) / 4);
  init_h<<<dim3(64), dim3(256), 0, stream>>>(h0, idx, Hb, flags, idxT);
  wtrans<<<dim3(V_ / 32, D_ / 32), dim3(256), 0, stream>>>(W_ih, b_ih, b_hh, Wtb);

  rnn_fused<<<dim3(NBLK + NWORK), dim3(512), 0, stream>>>(
      Rb, Wdiag, h0, Wtb, idxT, Hb, flags, Wb, b_o, out);

  logsoftmax<<<dim3(T_ * B_), dim3(256), 0, stream>>>(out);
}